// Round 9
// baseline (841.685 us; speedup 1.0000x reference)
//
#include <hip/hip_runtime.h>

// GCN 2-layer: out = S·relu(S·(X·W1)+b1)·W2 + b2, S = sym-norm adj + self loops.
// N=100000 nodes, E=1600000 edges, D: 128 -> 128 -> 64.
// GEMMs: MFMA bf16 hi/lo split (fp32-accurate). Aggregation operand stored
// bf16 pre-scaled by dinv[src], in COLBLOCK-MAJOR layout [P][(N+1)][16] so each
// 16-col block is 3.2MB (< 4MB per-XCD L2). Aggregation blocks pin themselves
// to their actual XCD (s_getreg XCC_ID) and process their XCD's colblock via
// per-colblock atomic chunk counters with stealing -> edge gathers are L2-hits.
// CSR built via bucketed counting sort (dst>>9) so all scatter is XCD-local.

#define D_IN  128
#define D_HID 128
#define D_OUT 64
#define NBSHIFT 9           // 512 nodes per bucket; NB = ceil(N/512) <= 256

typedef short short8 __attribute__((ext_vector_type(8)));
typedef float floatx4 __attribute__((ext_vector_type(4)));
typedef float floatx2 __attribute__((ext_vector_type(2)));

__device__ __forceinline__ unsigned short f2bf(float f) {
    unsigned int u = __float_as_uint(f);
    u += 0x7fffu + ((u >> 16) & 1u);   // RNE
    return (unsigned short)(u >> 16);
}
__device__ __forceinline__ float bf2f(unsigned short h) {
    return __uint_as_float((unsigned int)h << 16);
}
__device__ __forceinline__ float bf_lo(unsigned int u) { return __uint_as_float(u << 16); }
__device__ __forceinline__ float bf_hi(unsigned int u) { return __uint_as_float(u & 0xffff0000u); }

// actual XCD id of the CU this block runs on (HW_REG_XCC_ID = 20, gfx940+).
// Used ONLY as a locality preference -- correctness never depends on it.
__device__ __forceinline__ int xcc_id() {
    return __builtin_amdgcn_s_getreg(20 | (7 << 11)) & 7;  // offset 0, width 8
}

// ---------------- graph prep ----------------

__global__ __launch_bounds__(256) void k_zero_int(int* __restrict__ p, int n) {
    int i = blockIdx.x * 256 + threadIdx.x;
    if (i < n) p[i] = 0;
}

// bucket histogram: 8192 edges/block, LDS-reduced, one global add per (block,bucket)
__global__ __launch_bounds__(256) void k_bhist(const int* __restrict__ dst,
                                               int* __restrict__ bcnt, int E, int NB) {
    __shared__ int h[256];
    const int t = threadIdx.x;
    h[t] = 0;
    __syncthreads();
    const int base = blockIdx.x * 8192;
#pragma unroll
    for (int k = 0; k < 32; ++k) {
        int e = base + k * 256 + t;
        if (e < E) atomicAdd(&h[dst[e] >> NBSHIFT], 1);
    }
    __syncthreads();
    if (t < NB && h[t]) atomicAdd(&bcnt[t], h[t]);
}

// exclusive scan of bucket counts (NB <= 256), bases + cursors
__global__ __launch_bounds__(256) void k_bscan(const int* __restrict__ bcnt,
                                               int* __restrict__ bbase,
                                               int* __restrict__ bcur, int NB, int E) {
    __shared__ int ls[256];
    const int t = threadIdx.x;
    int v = (t < NB) ? bcnt[t] : 0;
    ls[t] = v;
    __syncthreads();
    for (int off = 1; off < 256; off <<= 1) {
        int y = (t >= off) ? ls[t - off] : 0;
        __syncthreads();
        ls[t] += y;
        __syncthreads();
    }
    if (t < NB) {
        bbase[t] = ls[t] - v;
        bcur[t]  = ls[t] - v;
    }
    if (t == 0) bbase[NB] = E;
}

// bin edges by bucket into ebuf (bucket-grouped, pairs kept in registers)
__global__ __launch_bounds__(256) void k_bin(const int* __restrict__ src,
                                             const int* __restrict__ dst,
                                             int2* __restrict__ ebuf,
                                             int* __restrict__ bcur, int E, int NB) {
    __shared__ int h[256];
    __shared__ int basep[256];
    const int t = threadIdx.x;
    h[t] = 0;
    __syncthreads();
    const int base = blockIdx.x * 4096;
    int s[16], d[16];
#pragma unroll
    for (int k = 0; k < 16; ++k) {
        int e = base + k * 256 + t;
        bool v = e < E;
        s[k] = v ? src[e] : 0;
        d[k] = v ? dst[e] : -1;
        if (v) atomicAdd(&h[d[k] >> NBSHIFT], 1);
    }
    __syncthreads();
    if (t < NB && h[t]) basep[t] = atomicAdd(&bcur[t], h[t]);
    __syncthreads();
    h[t] = 0;
    __syncthreads();
#pragma unroll
    for (int k = 0; k < 16; ++k) {
        if (d[k] >= 0) {
            int b = d[k] >> NBSHIFT;
            int r = atomicAdd(&h[b], 1);
            ebuf[basep[b] + r] = make_int2(s[k], d[k]);
        }
    }
}

// per-bucket: degree count + local scan -> rowstart, dinv, then csr fill via
// LDS cursors. All scatter stays inside the bucket's contiguous csr segment.
__global__ __launch_bounds__(256) void k_bfill(const int2* __restrict__ ebuf,
                                               const int* __restrict__ bbase,
                                               int* __restrict__ csr,
                                               int* __restrict__ rowstart,
                                               float* __restrict__ dinv,
                                               int N, int NB, int E) {
    __shared__ int cnt[512];
    __shared__ int pref[512];
    __shared__ int tsum[256];
    const int t = threadIdx.x;
    const int b = blockIdx.x;
    const int nb0 = b << NBSHIFT;
    const int NN = min(512, N - nb0);
    const int e0 = bbase[b], e1 = bbase[b + 1];

    cnt[t] = 0;
    cnt[t + 256] = 0;
    __syncthreads();
    for (int e = e0 + t; e < e1; e += 256)
        atomicAdd(&cnt[ebuf[e].y - nb0], 1);
    __syncthreads();

    int a0 = cnt[2 * t], a1 = cnt[2 * t + 1];
    tsum[t] = a0 + a1;
    __syncthreads();
    for (int off = 1; off < 256; off <<= 1) {
        int y = (t >= off) ? tsum[t - off] : 0;
        __syncthreads();
        tsum[t] += y;
        __syncthreads();
    }
    int excl = tsum[t] - (a0 + a1);
    pref[2 * t] = excl;
    pref[2 * t + 1] = excl + a0;
    __syncthreads();

    for (int nl = t; nl < NN; nl += 256) {
        rowstart[nb0 + nl] = e0 + pref[nl];
        dinv[nb0 + nl] = rsqrtf((float)(cnt[nl] + 1));  // +1 self loop
    }
    if (b == NB - 1 && t == 0) rowstart[N] = E;
    __syncthreads();  // rowstart reads of pref done before cursor mutation

    for (int e = e0 + t; e < e1; e += 256) {
        int2 ed = ebuf[e];
        int r = atomicAdd(&pref[ed.y - nb0], 1);
        csr[e0 + r] = ed.x;
    }
}

// zero pad rows (node index N) of both colblock-major buffers + chunk counters
__global__ void k_zero_pad(unsigned short* __restrict__ h1b,
                           unsigned short* __restrict__ h2b,
                           int* __restrict__ ctrs, int N) {
    int t = threadIdx.x;
    if (t < 128) h1b[((size_t)(t >> 4) * (N + 1) + N) * 16 + (t & 15)] = 0;
    if (t < 64)  h2b[((size_t)(t >> 4) * (N + 1) + N) * 16 + (t & 15)] = 0;
    if (t < 16)  ctrs[t] = 0;
}

// ---------------- W hi/lo split into MFMA B-fragment order ----------------
// Layout: Ws[half][kt][ct][lane][i], half0=hi, half1=lo.
// frag element (lane,i) <-> k = kt*32 + (lane>>4)*8 + i, n = ct*16 + (lane&15).

template <int DOUT_>
__global__ __launch_bounds__(256) void k_wsplit(const float* __restrict__ W,
                                                unsigned short* __restrict__ Ws) {
    constexpr int NCT = DOUT_ / 16;
    constexpr int HALF = 4 * NCT * 64 * 8;
    int id = blockIdx.x * 256 + threadIdx.x;
    if (id >= HALF) return;
    int i = id & 7;
    int lane = (id >> 3) & 63;
    int ctkt = id >> 9;                 // kt*NCT + ct
    int ct = ctkt % NCT, kt = ctkt / NCT;
    int k = kt * 32 + ((lane >> 4) << 3) + i;
    int n = ct * 16 + (lane & 15);
    float v = W[(size_t)k * DOUT_ + n];
    unsigned short h = f2bf(v);
    Ws[id] = h;
    Ws[HALF + id] = f2bf(v - bf2f(h));
}

// -------- MFMA GEMM (fp32 input): H = bf16((X@W)*dinv), X:[N,128] fp32 --------
// Output colblock-major: Hb[ct][(N+1)][16].

template <int DOUT_>
__global__ __launch_bounds__(256) void mfma_gemm(const float* __restrict__ X,
                                                 const unsigned short* __restrict__ Wsplit,
                                                 const float* __restrict__ dinv,
                                                 unsigned short* __restrict__ Hb,
                                                 int N) {
    constexpr int NCT = DOUT_ / 16;
    constexpr int HALF = 4 * NCT * 64 * 8;      // shorts per half
    __shared__ unsigned short lds[2 * HALF];    // 64 KB (D=128)

    const int t = threadIdx.x;
    {
        const int4* s4 = (const int4*)Wsplit;
        int4* d4 = (int4*)lds;
        constexpr int NV = 2 * HALF / 8;
        for (int i = t; i < NV; i += 256) d4[i] = s4[i];
    }
    __syncthreads();

    const int wave = t >> 6, lane = t & 63;
    const int grow = blockIdx.x * 64 + wave * 16 + (lane & 15);
    const int rowc = min(grow, N - 1);
    const int kl = (lane >> 4) << 3;

    floatx4 acc[NCT];
#pragma unroll
    for (int c = 0; c < NCT; ++c) acc[c] = (floatx4)0.f;

#pragma unroll
    for (int kt = 0; kt < 4; ++kt) {
        const float* xp = X + (size_t)rowc * 128 + kt * 32 + kl;
        float4 a0 = *(const float4*)xp;
        float4 a1 = *(const float4*)(xp + 4);
        float xs[8] = {a0.x, a0.y, a0.z, a0.w, a1.x, a1.y, a1.z, a1.w};
        short8 ah, al;
#pragma unroll
        for (int i = 0; i < 8; ++i) {
            unsigned short h = f2bf(xs[i]);
            ah[i] = (short)h;
            al[i] = (short)f2bf(xs[i] - bf2f(h));
        }
#pragma unroll
        for (int c = 0; c < NCT; ++c) {
            const int off = ((kt * NCT + c) * 64 + lane) * 8;
            short8 bh = *(const short8*)&lds[off];
            short8 bl = *(const short8*)&lds[HALF + off];
            acc[c] = __builtin_amdgcn_mfma_f32_16x16x32_bf16(ah, bh, acc[c], 0, 0, 0);
            acc[c] = __builtin_amdgcn_mfma_f32_16x16x32_bf16(al, bh, acc[c], 0, 0, 0);
            acc[c] = __builtin_amdgcn_mfma_f32_16x16x32_bf16(ah, bl, acc[c], 0, 0, 0);
        }
    }

    // C/D layout (verified): col = lane&15, row = (lane>>4)*4 + reg
    const int orow = blockIdx.x * 64 + wave * 16 + ((lane >> 4) << 2);
#pragma unroll
    for (int r = 0; r < 4; ++r) {
        int gr = orow + r;
        if (gr < N) {
            float dn = dinv[gr];
#pragma unroll
            for (int c = 0; c < NCT; ++c)
                Hb[((size_t)c * (N + 1) + gr) * 16 + (lane & 15)] = f2bf(acc[c][r] * dn);
        }
    }
}

// -------- MFMA GEMM (bf16 input, colblock-major): H2 = bf16((Xb@W)*dinv) --------
// Xb: [8][N][16] bf16 (no pad row); output Hb: [NCT][(N+1)][16].

template <int DOUT_>
__global__ __launch_bounds__(256) void mfma_gemm_b(const unsigned short* __restrict__ Xb,
                                                   const unsigned short* __restrict__ Wsplit,
                                                   const float* __restrict__ dinv,
                                                   unsigned short* __restrict__ Hb,
                                                   int N) {
    constexpr int NCT = DOUT_ / 16;
    constexpr int HALF = 4 * NCT * 64 * 8;
    __shared__ unsigned short lds[2 * HALF];    // 32 KB (D=64)

    const int t = threadIdx.x;
    {
        const int4* s4 = (const int4*)Wsplit;
        int4* d4 = (int4*)lds;
        constexpr int NV = 2 * HALF / 8;
        for (int i = t; i < NV; i += 256) d4[i] = s4[i];
    }
    __syncthreads();

    const int wave = t >> 6, lane = t & 63;
    const int grow = blockIdx.x * 64 + wave * 16 + (lane & 15);
    const int rowc = min(grow, N - 1);
    const int kl = (lane >> 4) << 3;

    floatx4 acc[NCT];
#pragma unroll
    for (int c = 0; c < NCT; ++c) acc[c] = (floatx4)0.f;

#pragma unroll
    for (int kt = 0; kt < 4; ++kt) {
        const int k0 = kt * 32 + kl;
        short8 ah = *(const short8*)&Xb[((size_t)(k0 >> 4) * N + rowc) * 16 + (k0 & 15)];
#pragma unroll
        for (int c = 0; c < NCT; ++c) {
            const int off = ((kt * NCT + c) * 64 + lane) * 8;
            short8 bh = *(const short8*)&lds[off];
            short8 bl = *(const short8*)&lds[HALF + off];
            acc[c] = __builtin_amdgcn_mfma_f32_16x16x32_bf16(ah, bh, acc[c], 0, 0, 0);
            acc[c] = __builtin_amdgcn_mfma_f32_16x16x32_bf16(ah, bl, acc[c], 0, 0, 0);
        }
    }

    const int orow = blockIdx.x * 64 + wave * 16 + ((lane >> 4) << 2);
#pragma unroll
    for (int r = 0; r < 4; ++r) {
        int gr = orow + r;
        if (gr < N) {
            float dn = dinv[gr];
#pragma unroll
            for (int c = 0; c < NCT; ++c)
                Hb[((size_t)c * (N + 1) + gr) * 16 + (lane & 15)] = f2bf(acc[c][r] * dn);
        }
    }
}

// ---------------- XCD-pinned column-partitioned aggregation ----------------
// Colblock p (16 cols, 3.2MB) is L2-resident on the XCD processing it. Blocks
// prefer colblock == their own XCD id and steal from others once drained, via
// per-colblock atomic chunk counters (chunk = 32 nodes). 8-lane group per node,
// 4B (2 cols) per lane. Tail lanes gather the zero pad row -> branch-free.

__global__ __launch_bounds__(256) void agg1_kernel(const unsigned short* __restrict__ Hc,  // [8][(N+1)][16]
                                                   const int* __restrict__ rowstart,
                                                   const int* __restrict__ csr_src,
                                                   const float* __restrict__ dinv,
                                                   const float* __restrict__ bias,
                                                   unsigned short* __restrict__ outc,      // [8][N][16]
                                                   int* __restrict__ ctrs, int N, int NC) {
    __shared__ int s_j;
    const int t = threadIdx.x;
    const int wave = t >> 6, lane = t & 63;
    const int g = lane >> 3, gl = lane & 7;
    const int x0 = xcc_id();
    for (int pp = 0; pp < 8; ++pp) {
        const int p = (x0 + pp) & 7;
        const size_t pb = (size_t)p * (N + 1) * 16;
        for (;;) {
            __syncthreads();
            if (t == 0) s_j = atomicAdd(&ctrs[p], 1);
            __syncthreads();
            const int j = s_j;
            if (j >= NC) break;
            const int n = j * 32 + wave * 8 + g;
            const bool live = n < N;
            const int e0 = live ? rowstart[n] : 0;
            const int deg = live ? rowstart[n + 1] - e0 : 0;
            int m = deg;
            m = max(m, __shfl_xor(m, 8));
            m = max(m, __shfl_xor(m, 16));
            m = max(m, __shfl_xor(m, 32));
            float a0 = 0.f, a1 = 0.f;
            for (int eb = 0; eb < m; eb += 8) {
                int s_l = (eb + gl < deg)
                              ? __builtin_nontemporal_load(csr_src + e0 + eb + gl)
                              : N;  // N = zero pad row
                int sj[8]; unsigned u[8];
#pragma unroll
                for (int q = 0; q < 8; ++q) sj[q] = __shfl(s_l, (g << 3) | q);
#pragma unroll
                for (int q = 0; q < 8; ++q)
                    u[q] = *reinterpret_cast<const unsigned*>(&Hc[pb + (size_t)sj[q] * 16 + gl * 2]);
#pragma unroll
                for (int q = 0; q < 8; ++q) { a0 += bf_lo(u[q]); a1 += bf_hi(u[q]); }
            }
            unsigned us = *reinterpret_cast<const unsigned*>(
                &Hc[pb + (size_t)(live ? n : N) * 16 + gl * 2]);  // self loop
            a0 += bf_lo(us);
            a1 += bf_hi(us);
            if (live) {
                const float dn = dinv[n];
                const int c0 = p * 16 + gl * 2;
                float o0 = fmaxf(fmaf(a0, dn, bias[c0]), 0.f);      // relu
                float o1 = fmaxf(fmaf(a1, dn, bias[c0 + 1]), 0.f);
                unsigned wv = (unsigned)f2bf(o0) | ((unsigned)f2bf(o1) << 16);
                *reinterpret_cast<unsigned*>(&outc[((size_t)p * N + n) * 16 + gl * 2]) = wv;
            }
        }
    }
}

__global__ __launch_bounds__(256) void agg2_kernel(const unsigned short* __restrict__ Hc,  // [4][(N+1)][16]
                                                   const int* __restrict__ rowstart,
                                                   const int* __restrict__ csr_src,
                                                   const float* __restrict__ dinv,
                                                   const float* __restrict__ bias,
                                                   float* __restrict__ out,
                                                   int* __restrict__ ctrs, int N, int NC) {
    __shared__ int s_j;
    const int t = threadIdx.x;
    const int wave = t >> 6, lane = t & 63;
    const int g = lane >> 3, gl = lane & 7;
    const int x0 = xcc_id() & 3;
    for (int pp = 0; pp < 4; ++pp) {
        const int p = (x0 + pp) & 3;
        const size_t pb = (size_t)p * (N + 1) * 16;
        for (;;) {
            __syncthreads();
            if (t == 0) s_j = atomicAdd(&ctrs[p], 1);
            __syncthreads();
            const int j = s_j;
            if (j >= NC) break;
            const int n = j * 32 + wave * 8 + g;
            const bool live = n < N;
            const int e0 = live ? rowstart[n] : 0;
            const int deg = live ? rowstart[n + 1] - e0 : 0;
            int m = deg;
            m = max(m, __shfl_xor(m, 8));
            m = max(m, __shfl_xor(m, 16));
            m = max(m, __shfl_xor(m, 32));
            float a0 = 0.f, a1 = 0.f;
            for (int eb = 0; eb < m; eb += 8) {
                int s_l = (eb + gl < deg)
                              ? __builtin_nontemporal_load(csr_src + e0 + eb + gl)
                              : N;
                int sj[8]; unsigned u[8];
#pragma unroll
                for (int q = 0; q < 8; ++q) sj[q] = __shfl(s_l, (g << 3) | q);
#pragma unroll
                for (int q = 0; q < 8; ++q)
                    u[q] = *reinterpret_cast<const unsigned*>(&Hc[pb + (size_t)sj[q] * 16 + gl * 2]);
#pragma unroll
                for (int q = 0; q < 8; ++q) { a0 += bf_lo(u[q]); a1 += bf_hi(u[q]); }
            }
            unsigned us = *reinterpret_cast<const unsigned*>(
                &Hc[pb + (size_t)(live ? n : N) * 16 + gl * 2]);  // self loop
            a0 += bf_lo(us);
            a1 += bf_hi(us);
            if (live) {
                const float dn = dinv[n];
                const int c0 = p * 16 + gl * 2;
                floatx2 o;
                o.x = fmaf(a0, dn, bias[c0]);
                o.y = fmaf(a1, dn, bias[c0 + 1]);
                __builtin_nontemporal_store(o, reinterpret_cast<floatx2*>(
                    &out[(size_t)n * 64 + p * 16 + gl * 2]));
            }
        }
    }
}

// ---------------- launch ----------------

extern "C" void kernel_launch(void* const* d_in, const int* in_sizes, int n_in,
                              void* d_out, int out_size, void* d_ws, size_t ws_size,
                              hipStream_t stream) {
    const float* x  = (const float*)d_in[0];
    const int*   ei = (const int*)d_in[1];
    const float* W1 = (const float*)d_in[2];
    const float* b1 = (const float*)d_in[3];
    const float* W2 = (const float*)d_in[4];
    const float* b2 = (const float*)d_in[5];
    float* out = (float*)d_out;

    const int N = in_sizes[0] / D_IN;
    const int E = in_sizes[1] / 2;
    const int* src = ei;
    const int* dst = ei + E;
    const int NB = (N + 511) >> NBSHIFT;   // <= 256

    char* w = (char*)d_ws;
    auto alloc = [&](size_t bytes) {
        char* p = w;
        w += (bytes + 255) & ~(size_t)255;
        return p;
    };
    int*   rowstart  = (int*)alloc((size_t)(N + 1) * 4);
    float* dinv      = (float*)alloc((size_t)N * 4);
    int*   csr       = (int*)alloc((size_t)E * 4);
    unsigned short* h1b = (unsigned short*)alloc((size_t)(N + 1) * D_HID * 2);  // [8][(N+1)][16]
    unsigned short* h2b = (unsigned short*)alloc((size_t)(N + 1) * D_OUT * 2);  // [4][(N+1)][16]
    unsigned short* hgb = (unsigned short*)alloc((size_t)N * D_HID * 2);        // [8][N][16]; also ebuf
    int*   bcnt      = (int*)alloc((size_t)NB * 4);
    int*   bbase     = (int*)alloc((size_t)(NB + 1) * 4);
    int*   bcur      = (int*)alloc((size_t)NB * 4);
    int*   ctrs      = (int*)alloc(16 * 4);
    unsigned short* w1s = (unsigned short*)alloc(2 * 4 * (D_HID / 16) * 64 * 8 * 2);
    unsigned short* w2s = (unsigned short*)alloc(2 * 4 * (D_OUT / 16) * 64 * 8 * 2);
    int2*  ebuf      = (int2*)hgb;   // E*8 = 12.8MB <= N*128*2 = 25.6MB; dead before agg1

    k_zero_int<<<1, 256, 0, stream>>>(bcnt, NB);
    k_bhist<<<(E + 8191) / 8192, 256, 0, stream>>>(dst, bcnt, E, NB);
    k_bscan<<<1, 256, 0, stream>>>(bcnt, bbase, bcur, NB, E);
    k_bin<<<(E + 4095) / 4096, 256, 0, stream>>>(src, dst, ebuf, bcur, E, NB);
    k_bfill<<<NB, 256, 0, stream>>>(ebuf, bbase, csr, rowstart, dinv, N, NB, E);
    k_zero_pad<<<1, 128, 0, stream>>>(h1b, h2b, ctrs, N);
    k_wsplit<D_HID><<<(4 * (D_HID / 16) * 64 * 8 + 255) / 256, 256, 0, stream>>>(W1, w1s);
    k_wsplit<D_OUT><<<(4 * (D_OUT / 16) * 64 * 8 + 255) / 256, 256, 0, stream>>>(W2, w2s);

    const int NC = (N + 31) / 32;   // 32-node chunks per colblock

    mfma_gemm<D_HID><<<(N + 63) / 64, 256, 0, stream>>>(x, w1s, dinv, h1b, N);
    agg1_kernel<<<2048, 256, 0, stream>>>(h1b, rowstart, csr, dinv, b1, hgb, ctrs, N, NC);
    mfma_gemm_b<D_OUT><<<(N + 63) / 64, 256, 0, stream>>>(hgb, w2s, dinv, h2b, N);
    agg2_kernel<<<2048, 256, 0, stream>>>(h2b, rowstart, csr, dinv, b2, out, ctrs + 8, N, NC);
}

// Round 10
// 308.155 us; speedup vs baseline: 2.7314x; 2.7314x over previous
//
#include <hip/hip_runtime.h>

// GCN 2-layer: out = S·relu(S·(X·W1)+b1)·W2 + b2, S = sym-norm adj + self loops.
// N=100000 nodes, E=1600000 edges, D: 128 -> 128 -> 64.
// GEMMs: MFMA bf16 hi/lo split (fp32-accurate). Aggregation operand stored
// bf16 pre-scaled by dinv[src], COLBLOCK-MAJOR [P][(N+1)][16]: each 16-col
// block is 3.2MB (< 4MB per-XCD L2). Aggregation blocks statically map
// colblock = blockIdx&7 (round-robin dispatch -> same-p blocks share an XCD,
// so each XCD's gathers stay L2-resident). No atomics, no barriers (round-9
// post-mortem: contended single-line counters serialized the kernel).
// 2-lane groups x 16B/lane = one 32B colblock row per gather.
// CSR built via bucketed counting sort (dst>>9) so all scatter is XCD-local.

#define D_IN  128
#define D_HID 128
#define D_OUT 64
#define NBSHIFT 9           // 512 nodes per bucket; NB = ceil(N/512) <= 256

typedef short short8 __attribute__((ext_vector_type(8)));
typedef float floatx4 __attribute__((ext_vector_type(4)));

__device__ __forceinline__ unsigned short f2bf(float f) {
    unsigned int u = __float_as_uint(f);
    u += 0x7fffu + ((u >> 16) & 1u);   // RNE
    return (unsigned short)(u >> 16);
}
__device__ __forceinline__ float bf2f(unsigned short h) {
    return __uint_as_float((unsigned int)h << 16);
}
__device__ __forceinline__ float bf_lo(unsigned int u) { return __uint_as_float(u << 16); }
__device__ __forceinline__ float bf_hi(unsigned int u) { return __uint_as_float(u & 0xffff0000u); }

// ---------------- graph prep ----------------

__global__ __launch_bounds__(256) void k_zero_int(int* __restrict__ p, int n) {
    int i = blockIdx.x * 256 + threadIdx.x;
    if (i < n) p[i] = 0;
}

// bucket histogram: 8192 edges/block, LDS-reduced, one global add per (block,bucket)
__global__ __launch_bounds__(256) void k_bhist(const int* __restrict__ dst,
                                               int* __restrict__ bcnt, int E, int NB) {
    __shared__ int h[256];
    const int t = threadIdx.x;
    h[t] = 0;
    __syncthreads();
    const int base = blockIdx.x * 8192;
#pragma unroll
    for (int k = 0; k < 32; ++k) {
        int e = base + k * 256 + t;
        if (e < E) atomicAdd(&h[dst[e] >> NBSHIFT], 1);
    }
    __syncthreads();
    if (t < NB && h[t]) atomicAdd(&bcnt[t], h[t]);
}

// exclusive scan of bucket counts (NB <= 256), bases + cursors
__global__ __launch_bounds__(256) void k_bscan(const int* __restrict__ bcnt,
                                               int* __restrict__ bbase,
                                               int* __restrict__ bcur, int NB, int E) {
    __shared__ int ls[256];
    const int t = threadIdx.x;
    int v = (t < NB) ? bcnt[t] : 0;
    ls[t] = v;
    __syncthreads();
    for (int off = 1; off < 256; off <<= 1) {
        int y = (t >= off) ? ls[t - off] : 0;
        __syncthreads();
        ls[t] += y;
        __syncthreads();
    }
    if (t < NB) {
        bbase[t] = ls[t] - v;
        bcur[t]  = ls[t] - v;
    }
    if (t == 0) bbase[NB] = E;
}

// bin edges by bucket into ebuf (bucket-grouped, pairs kept in registers)
__global__ __launch_bounds__(256) void k_bin(const int* __restrict__ src,
                                             const int* __restrict__ dst,
                                             int2* __restrict__ ebuf,
                                             int* __restrict__ bcur, int E, int NB) {
    __shared__ int h[256];
    __shared__ int basep[256];
    const int t = threadIdx.x;
    h[t] = 0;
    __syncthreads();
    const int base = blockIdx.x * 4096;
    int s[16], d[16];
#pragma unroll
    for (int k = 0; k < 16; ++k) {
        int e = base + k * 256 + t;
        bool v = e < E;
        s[k] = v ? src[e] : 0;
        d[k] = v ? dst[e] : -1;
        if (v) atomicAdd(&h[d[k] >> NBSHIFT], 1);
    }
    __syncthreads();
    if (t < NB && h[t]) basep[t] = atomicAdd(&bcur[t], h[t]);
    __syncthreads();
    h[t] = 0;
    __syncthreads();
#pragma unroll
    for (int k = 0; k < 16; ++k) {
        if (d[k] >= 0) {
            int b = d[k] >> NBSHIFT;
            int r = atomicAdd(&h[b], 1);
            ebuf[basep[b] + r] = make_int2(s[k], d[k]);
        }
    }
}

// per-bucket: degree count + local scan -> rowstart, dinv, then csr fill via
// LDS cursors. All scatter stays inside the bucket's contiguous csr segment.
__global__ __launch_bounds__(256) void k_bfill(const int2* __restrict__ ebuf,
                                               const int* __restrict__ bbase,
                                               int* __restrict__ csr,
                                               int* __restrict__ rowstart,
                                               float* __restrict__ dinv,
                                               int N, int NB, int E) {
    __shared__ int cnt[512];
    __shared__ int pref[512];
    __shared__ int tsum[256];
    const int t = threadIdx.x;
    const int b = blockIdx.x;
    const int nb0 = b << NBSHIFT;
    const int NN = min(512, N - nb0);
    const int e0 = bbase[b], e1 = bbase[b + 1];

    cnt[t] = 0;
    cnt[t + 256] = 0;
    __syncthreads();
    for (int e = e0 + t; e < e1; e += 256)
        atomicAdd(&cnt[ebuf[e].y - nb0], 1);
    __syncthreads();

    int a0 = cnt[2 * t], a1 = cnt[2 * t + 1];
    tsum[t] = a0 + a1;
    __syncthreads();
    for (int off = 1; off < 256; off <<= 1) {
        int y = (t >= off) ? tsum[t - off] : 0;
        __syncthreads();
        tsum[t] += y;
        __syncthreads();
    }
    int excl = tsum[t] - (a0 + a1);
    pref[2 * t] = excl;
    pref[2 * t + 1] = excl + a0;
    __syncthreads();

    for (int nl = t; nl < NN; nl += 256) {
        rowstart[nb0 + nl] = e0 + pref[nl];
        dinv[nb0 + nl] = rsqrtf((float)(cnt[nl] + 1));  // +1 self loop
    }
    if (b == NB - 1 && t == 0) rowstart[N] = E;
    __syncthreads();  // rowstart reads of pref done before cursor mutation

    for (int e = e0 + t; e < e1; e += 256) {
        int2 ed = ebuf[e];
        int r = atomicAdd(&pref[ed.y - nb0], 1);
        csr[e0 + r] = ed.x;
    }
}

// zero pad rows (node index N) of both colblock-major buffers
__global__ void k_zero_pad(unsigned short* __restrict__ h1b,
                           unsigned short* __restrict__ h2b, int N) {
    int t = threadIdx.x;
    if (t < 128) h1b[((size_t)(t >> 4) * (N + 1) + N) * 16 + (t & 15)] = 0;
    if (t < 64)  h2b[((size_t)(t >> 4) * (N + 1) + N) * 16 + (t & 15)] = 0;
}

// ---------------- W hi/lo split into MFMA B-fragment order ----------------
// Layout: Ws[half][kt][ct][lane][i], half0=hi, half1=lo.
// frag element (lane,i) <-> k = kt*32 + (lane>>4)*8 + i, n = ct*16 + (lane&15).

template <int DOUT_>
__global__ __launch_bounds__(256) void k_wsplit(const float* __restrict__ W,
                                                unsigned short* __restrict__ Ws) {
    constexpr int NCT = DOUT_ / 16;
    constexpr int HALF = 4 * NCT * 64 * 8;
    int id = blockIdx.x * 256 + threadIdx.x;
    if (id >= HALF) return;
    int i = id & 7;
    int lane = (id >> 3) & 63;
    int ctkt = id >> 9;                 // kt*NCT + ct
    int ct = ctkt % NCT, kt = ctkt / NCT;
    int k = kt * 32 + ((lane >> 4) << 3) + i;
    int n = ct * 16 + (lane & 15);
    float v = W[(size_t)k * DOUT_ + n];
    unsigned short h = f2bf(v);
    Ws[id] = h;
    Ws[HALF + id] = f2bf(v - bf2f(h));
}

// -------- MFMA GEMM (fp32 input): H = bf16((X@W)*dinv), X:[N,128] fp32 --------
// Output colblock-major: Hb[ct][(N+1)][16].

template <int DOUT_>
__global__ __launch_bounds__(256) void mfma_gemm(const float* __restrict__ X,
                                                 const unsigned short* __restrict__ Wsplit,
                                                 const float* __restrict__ dinv,
                                                 unsigned short* __restrict__ Hb,
                                                 int N) {
    constexpr int NCT = DOUT_ / 16;
    constexpr int HALF = 4 * NCT * 64 * 8;      // shorts per half
    __shared__ unsigned short lds[2 * HALF];    // 64 KB (D=128)

    const int t = threadIdx.x;
    {
        const int4* s4 = (const int4*)Wsplit;
        int4* d4 = (int4*)lds;
        constexpr int NV = 2 * HALF / 8;
        for (int i = t; i < NV; i += 256) d4[i] = s4[i];
    }
    __syncthreads();

    const int wave = t >> 6, lane = t & 63;
    const int grow = blockIdx.x * 64 + wave * 16 + (lane & 15);
    const int rowc = min(grow, N - 1);
    const int kl = (lane >> 4) << 3;

    floatx4 acc[NCT];
#pragma unroll
    for (int c = 0; c < NCT; ++c) acc[c] = (floatx4)0.f;

#pragma unroll
    for (int kt = 0; kt < 4; ++kt) {
        const float* xp = X + (size_t)rowc * 128 + kt * 32 + kl;
        float4 a0 = *(const float4*)xp;
        float4 a1 = *(const float4*)(xp + 4);
        float xs[8] = {a0.x, a0.y, a0.z, a0.w, a1.x, a1.y, a1.z, a1.w};
        short8 ah, al;
#pragma unroll
        for (int i = 0; i < 8; ++i) {
            unsigned short h = f2bf(xs[i]);
            ah[i] = (short)h;
            al[i] = (short)f2bf(xs[i] - bf2f(h));
        }
#pragma unroll
        for (int c = 0; c < NCT; ++c) {
            const int off = ((kt * NCT + c) * 64 + lane) * 8;
            short8 bh = *(const short8*)&lds[off];
            short8 bl = *(const short8*)&lds[HALF + off];
            acc[c] = __builtin_amdgcn_mfma_f32_16x16x32_bf16(ah, bh, acc[c], 0, 0, 0);
            acc[c] = __builtin_amdgcn_mfma_f32_16x16x32_bf16(al, bh, acc[c], 0, 0, 0);
            acc[c] = __builtin_amdgcn_mfma_f32_16x16x32_bf16(ah, bl, acc[c], 0, 0, 0);
        }
    }

    // C/D layout (verified): col = lane&15, row = (lane>>4)*4 + reg
    const int orow = blockIdx.x * 64 + wave * 16 + ((lane >> 4) << 2);
#pragma unroll
    for (int r = 0; r < 4; ++r) {
        int gr = orow + r;
        if (gr < N) {
            float dn = dinv[gr];
#pragma unroll
            for (int c = 0; c < NCT; ++c)
                Hb[((size_t)c * (N + 1) + gr) * 16 + (lane & 15)] = f2bf(acc[c][r] * dn);
        }
    }
}

// -------- MFMA GEMM (bf16 input, colblock-major): H2 = bf16((Xb@W)*dinv) --------
// Xb: [8][N][16] bf16 (no pad row); output Hb: [NCT][(N+1)][16].

template <int DOUT_>
__global__ __launch_bounds__(256) void mfma_gemm_b(const unsigned short* __restrict__ Xb,
                                                   const unsigned short* __restrict__ Wsplit,
                                                   const float* __restrict__ dinv,
                                                   unsigned short* __restrict__ Hb,
                                                   int N) {
    constexpr int NCT = DOUT_ / 16;
    constexpr int HALF = 4 * NCT * 64 * 8;
    __shared__ unsigned short lds[2 * HALF];    // 32 KB (D=64)

    const int t = threadIdx.x;
    {
        const int4* s4 = (const int4*)Wsplit;
        int4* d4 = (int4*)lds;
        constexpr int NV = 2 * HALF / 8;
        for (int i = t; i < NV; i += 256) d4[i] = s4[i];
    }
    __syncthreads();

    const int wave = t >> 6, lane = t & 63;
    const int grow = blockIdx.x * 64 + wave * 16 + (lane & 15);
    const int rowc = min(grow, N - 1);
    const int kl = (lane >> 4) << 3;

    floatx4 acc[NCT];
#pragma unroll
    for (int c = 0; c < NCT; ++c) acc[c] = (floatx4)0.f;

#pragma unroll
    for (int kt = 0; kt < 4; ++kt) {
        const int k0 = kt * 32 + kl;
        short8 ah = *(const short8*)&Xb[((size_t)(k0 >> 4) * N + rowc) * 16 + (k0 & 15)];
#pragma unroll
        for (int c = 0; c < NCT; ++c) {
            const int off = ((kt * NCT + c) * 64 + lane) * 8;
            short8 bh = *(const short8*)&lds[off];
            short8 bl = *(const short8*)&lds[HALF + off];
            acc[c] = __builtin_amdgcn_mfma_f32_16x16x32_bf16(ah, bh, acc[c], 0, 0, 0);
            acc[c] = __builtin_amdgcn_mfma_f32_16x16x32_bf16(ah, bl, acc[c], 0, 0, 0);
        }
    }

    const int orow = blockIdx.x * 64 + wave * 16 + ((lane >> 4) << 2);
#pragma unroll
    for (int r = 0; r < 4; ++r) {
        int gr = orow + r;
        if (gr < N) {
            float dn = dinv[gr];
#pragma unroll
            for (int c = 0; c < NCT; ++c)
                Hb[((size_t)c * (N + 1) + gr) * 16 + (lane & 15)] = f2bf(acc[c][r] * dn);
        }
    }
}

// ---------------- static XCD-partitioned column-blocked aggregation ----------------
// colblock p = blockIdx&7 (round-robin dispatch -> same-p blocks on one XCD,
// 3.2MB colblock L2-resident). 2-lane group per node: 16B/lane = 32B row.
// 32 nodes/wave, 128 nodes/block. Per-group divergent degree loop; OOB edge
// slots gather the zero pad row (index N). csr read nontemporal (streams 8x,
// must not evict the resident colblock).

__global__ __launch_bounds__(256) void agg1_kernel(const uint4* __restrict__ H4,  // [8][(N+1)][2] uint4
                                                   const int* __restrict__ rowstart,
                                                   const int* __restrict__ csr_src,
                                                   const float* __restrict__ dinv,
                                                   const float* __restrict__ bias,
                                                   unsigned short* __restrict__ outc,  // [8][N][16]
                                                   int N) {
    const int p = blockIdx.x & 7;
    const int chunk = blockIdx.x >> 3;
    const int t = threadIdx.x;
    const int wave = t >> 6, lane = t & 63;
    const int g = lane >> 1, gl = lane & 1;
    const int n = chunk * 128 + wave * 32 + g;
    if (n >= N) return;
    const uint4* __restrict__ Hp = H4 + (size_t)p * (N + 1) * 2;
    const int e0 = rowstart[n];
    const int deg = rowstart[n + 1] - e0;

    float acc[8] = {0.f, 0.f, 0.f, 0.f, 0.f, 0.f, 0.f, 0.f};
    for (int eb = 0; eb < deg; eb += 8) {
        int s[4];
#pragma unroll
        for (int k = 0; k < 4; ++k) {
            int idx = eb + 2 * k + gl;
            s[k] = (idx < deg) ? __builtin_nontemporal_load(csr_src + e0 + idx) : N;
        }
        int sj[8];
#pragma unroll
        for (int k = 0; k < 4; ++k) {
            sj[2 * k]     = __shfl(s[k], (g << 1));
            sj[2 * k + 1] = __shfl(s[k], (g << 1) | 1);
        }
        uint4 u[8];
#pragma unroll
        for (int q = 0; q < 8; ++q) u[q] = Hp[(size_t)sj[q] * 2 + gl];
#pragma unroll
        for (int q = 0; q < 8; ++q) {
            acc[0] += bf_lo(u[q].x); acc[1] += bf_hi(u[q].x);
            acc[2] += bf_lo(u[q].y); acc[3] += bf_hi(u[q].y);
            acc[4] += bf_lo(u[q].z); acc[5] += bf_hi(u[q].z);
            acc[6] += bf_lo(u[q].w); acc[7] += bf_hi(u[q].w);
        }
    }
    uint4 us = Hp[(size_t)n * 2 + gl];   // self loop
    acc[0] += bf_lo(us.x); acc[1] += bf_hi(us.x);
    acc[2] += bf_lo(us.y); acc[3] += bf_hi(us.y);
    acc[4] += bf_lo(us.z); acc[5] += bf_hi(us.z);
    acc[6] += bf_lo(us.w); acc[7] += bf_hi(us.w);

    const float dn = dinv[n];
    const float* bp = bias + p * 16 + gl * 8;
    unsigned short o[8];
#pragma unroll
    for (int j = 0; j < 8; ++j)
        o[j] = f2bf(fmaxf(fmaf(acc[j], dn, bp[j]), 0.f));  // relu
    *reinterpret_cast<uint4*>(&outc[((size_t)p * N + n) * 16 + gl * 8]) =
        *reinterpret_cast<const uint4*>(o);
}

__global__ __launch_bounds__(256) void agg2_kernel(const uint4* __restrict__ H4,  // [4][(N+1)][2] uint4
                                                   const int* __restrict__ rowstart,
                                                   const int* __restrict__ csr_src,
                                                   const float* __restrict__ dinv,
                                                   const float* __restrict__ bias,
                                                   float* __restrict__ out,
                                                   int N, int NCH) {
    const int slot = blockIdx.x & 7;
    const int p = slot & 3;
    const int chunk = (blockIdx.x >> 3) * 2 + (slot >> 2);
    if (chunk >= NCH) return;
    const int t = threadIdx.x;
    const int wave = t >> 6, lane = t & 63;
    const int g = lane >> 1, gl = lane & 1;
    const int n = chunk * 128 + wave * 32 + g;
    if (n >= N) return;
    const uint4* __restrict__ Hp = H4 + (size_t)p * (N + 1) * 2;
    const int e0 = rowstart[n];
    const int deg = rowstart[n + 1] - e0;

    float acc[8] = {0.f, 0.f, 0.f, 0.f, 0.f, 0.f, 0.f, 0.f};
    for (int eb = 0; eb < deg; eb += 8) {
        int s[4];
#pragma unroll
        for (int k = 0; k < 4; ++k) {
            int idx = eb + 2 * k + gl;
            s[k] = (idx < deg) ? __builtin_nontemporal_load(csr_src + e0 + idx) : N;
        }
        int sj[8];
#pragma unroll
        for (int k = 0; k < 4; ++k) {
            sj[2 * k]     = __shfl(s[k], (g << 1));
            sj[2 * k + 1] = __shfl(s[k], (g << 1) | 1);
        }
        uint4 u[8];
#pragma unroll
        for (int q = 0; q < 8; ++q) u[q] = Hp[(size_t)sj[q] * 2 + gl];
#pragma unroll
        for (int q = 0; q < 8; ++q) {
            acc[0] += bf_lo(u[q].x); acc[1] += bf_hi(u[q].x);
            acc[2] += bf_lo(u[q].y); acc[3] += bf_hi(u[q].y);
            acc[4] += bf_lo(u[q].z); acc[5] += bf_hi(u[q].z);
            acc[6] += bf_lo(u[q].w); acc[7] += bf_hi(u[q].w);
        }
    }
    uint4 us = Hp[(size_t)n * 2 + gl];   // self loop
    acc[0] += bf_lo(us.x); acc[1] += bf_hi(us.x);
    acc[2] += bf_lo(us.y); acc[3] += bf_hi(us.y);
    acc[4] += bf_lo(us.z); acc[5] += bf_hi(us.z);
    acc[6] += bf_lo(us.w); acc[7] += bf_hi(us.w);

    const float dn = dinv[n];
    const float* bp = bias + p * 16 + gl * 8;
    float4 o0, o1;
    o0.x = fmaf(acc[0], dn, bp[0]);
    o0.y = fmaf(acc[1], dn, bp[1]);
    o0.z = fmaf(acc[2], dn, bp[2]);
    o0.w = fmaf(acc[3], dn, bp[3]);
    o1.x = fmaf(acc[4], dn, bp[4]);
    o1.y = fmaf(acc[5], dn, bp[5]);
    o1.z = fmaf(acc[6], dn, bp[6]);
    o1.w = fmaf(acc[7], dn, bp[7]);
    float* op = out + (size_t)n * 64 + p * 16 + gl * 8;
    *reinterpret_cast<float4*>(op) = o0;
    *reinterpret_cast<float4*>(op + 4) = o1;
}

// ---------------- launch ----------------

extern "C" void kernel_launch(void* const* d_in, const int* in_sizes, int n_in,
                              void* d_out, int out_size, void* d_ws, size_t ws_size,
                              hipStream_t stream) {
    const float* x  = (const float*)d_in[0];
    const int*   ei = (const int*)d_in[1];
    const float* W1 = (const float*)d_in[2];
    const float* b1 = (const float*)d_in[3];
    const float* W2 = (const float*)d_in[4];
    const float* b2 = (const float*)d_in[5];
    float* out = (float*)d_out;

    const int N = in_sizes[0] / D_IN;
    const int E = in_sizes[1] / 2;
    const int* src = ei;
    const int* dst = ei + E;
    const int NB = (N + 511) >> NBSHIFT;   // <= 256

    char* w = (char*)d_ws;
    auto alloc = [&](size_t bytes) {
        char* p = w;
        w += (bytes + 255) & ~(size_t)255;
        return p;
    };
    int*   rowstart  = (int*)alloc((size_t)(N + 1) * 4);
    float* dinv      = (float*)alloc((size_t)N * 4);
    int*   csr       = (int*)alloc((size_t)E * 4);
    unsigned short* h1b = (unsigned short*)alloc((size_t)(N + 1) * D_HID * 2);  // [8][(N+1)][16]
    unsigned short* h2b = (unsigned short*)alloc((size_t)(N + 1) * D_OUT * 2);  // [4][(N+1)][16]
    unsigned short* hgb = (unsigned short*)alloc((size_t)N * D_HID * 2);        // [8][N][16]; also ebuf
    int*   bcnt      = (int*)alloc((size_t)NB * 4);
    int*   bbase     = (int*)alloc((size_t)(NB + 1) * 4);
    int*   bcur      = (int*)alloc((size_t)NB * 4);
    unsigned short* w1s = (unsigned short*)alloc(2 * 4 * (D_HID / 16) * 64 * 8 * 2);
    unsigned short* w2s = (unsigned short*)alloc(2 * 4 * (D_OUT / 16) * 64 * 8 * 2);
    int2*  ebuf      = (int2*)hgb;   // E*8 = 12.8MB <= N*128*2 = 25.6MB; dead before agg1

    k_zero_int<<<1, 256, 0, stream>>>(bcnt, NB);
    k_bhist<<<(E + 8191) / 8192, 256, 0, stream>>>(dst, bcnt, E, NB);
    k_bscan<<<1, 256, 0, stream>>>(bcnt, bbase, bcur, NB, E);
    k_bin<<<(E + 4095) / 4096, 256, 0, stream>>>(src, dst, ebuf, bcur, E, NB);
    k_bfill<<<NB, 256, 0, stream>>>(ebuf, bbase, csr, rowstart, dinv, N, NB, E);
    k_zero_pad<<<1, 128, 0, stream>>>(h1b, h2b, N);
    k_wsplit<D_HID><<<(4 * (D_HID / 16) * 64 * 8 + 255) / 256, 256, 0, stream>>>(W1, w1s);
    k_wsplit<D_OUT><<<(4 * (D_OUT / 16) * 64 * 8 + 255) / 256, 256, 0, stream>>>(W2, w2s);

    const int NCH = (N + 127) / 128;   // 128-node chunks

    mfma_gemm<D_HID><<<(N + 63) / 64, 256, 0, stream>>>(x, w1s, dinv, h1b, N);
    agg1_kernel<<<NCH * 8, 256, 0, stream>>>((const uint4*)h1b, rowstart, csr,
                                             dinv, b1, hgb, N);
    mfma_gemm_b<D_OUT><<<(N + 63) / 64, 256, 0, stream>>>(hgb, w2s, dinv, h2b, N);
    agg2_kernel<<<((NCH + 1) / 2) * 8, 256, 0, stream>>>((const uint4*)h2b, rowstart, csr,
                                                         dinv, b2, out, N, NCH);
}

// Round 11
// 287.360 us; speedup vs baseline: 2.9290x; 1.0724x over previous
//
#include <hip/hip_runtime.h>

// GCN 2-layer: out = S·relu(S·(X·W1)+b1)·W2 + b2, S = sym-norm adj + self loops.
// N=100000 nodes, E=1600000 edges, D: 128 -> 128 -> 64.
// GEMMs: MFMA bf16 hi/lo split (fp32-accurate). Aggregation operand stored
// bf16 pre-scaled by dinv[src], COLBLOCK-MAJOR [P][(N+1)][16]: each 16-col
// block is 3.2MB (< 4MB per-XCD L2). Agg blocks statically map colblock =
// blockIdx&7 (round-robin dispatch -> same-p blocks share an XCD; validated
// round 10: FETCH 163->88MB). Gather shape: 8-lane groups x 4B/lane = one
// 32B row/group, 8 rows per instruction (round-10 post-mortem: 2-lane groups
// gave 32-line-divergent instructions -> TA-bound, 121us).
// CSR built via bucketed counting sort (dst>>9) so all scatter is XCD-local.

#define D_IN  128
#define D_HID 128
#define D_OUT 64
#define NBSHIFT 9           // 512 nodes per bucket; NB = ceil(N/512) <= 256

typedef short short8 __attribute__((ext_vector_type(8)));
typedef float floatx4 __attribute__((ext_vector_type(4)));
typedef float floatx2 __attribute__((ext_vector_type(2)));

__device__ __forceinline__ unsigned short f2bf(float f) {
    unsigned int u = __float_as_uint(f);
    u += 0x7fffu + ((u >> 16) & 1u);   // RNE
    return (unsigned short)(u >> 16);
}
__device__ __forceinline__ float bf2f(unsigned short h) {
    return __uint_as_float((unsigned int)h << 16);
}
__device__ __forceinline__ float bf_lo(unsigned int u) { return __uint_as_float(u << 16); }
__device__ __forceinline__ float bf_hi(unsigned int u) { return __uint_as_float(u & 0xffff0000u); }

// ---------------- graph prep ----------------

__global__ __launch_bounds__(256) void k_zero_int(int* __restrict__ p, int n) {
    int i = blockIdx.x * 256 + threadIdx.x;
    if (i < n) p[i] = 0;
}

// bucket histogram: 8192 edges/block, LDS-reduced, one global add per (block,bucket)
__global__ __launch_bounds__(256) void k_bhist(const int* __restrict__ dst,
                                               int* __restrict__ bcnt, int E, int NB) {
    __shared__ int h[256];
    const int t = threadIdx.x;
    h[t] = 0;
    __syncthreads();
    const int base = blockIdx.x * 8192;
#pragma unroll
    for (int k = 0; k < 32; ++k) {
        int e = base + k * 256 + t;
        if (e < E) atomicAdd(&h[dst[e] >> NBSHIFT], 1);
    }
    __syncthreads();
    if (t < NB && h[t]) atomicAdd(&bcnt[t], h[t]);
}

// exclusive scan of bucket counts (NB <= 256), bases + cursors
__global__ __launch_bounds__(256) void k_bscan(const int* __restrict__ bcnt,
                                               int* __restrict__ bbase,
                                               int* __restrict__ bcur, int NB, int E) {
    __shared__ int ls[256];
    const int t = threadIdx.x;
    int v = (t < NB) ? bcnt[t] : 0;
    ls[t] = v;
    __syncthreads();
    for (int off = 1; off < 256; off <<= 1) {
        int y = (t >= off) ? ls[t - off] : 0;
        __syncthreads();
        ls[t] += y;
        __syncthreads();
    }
    if (t < NB) {
        bbase[t] = ls[t] - v;
        bcur[t]  = ls[t] - v;
    }
    if (t == 0) bbase[NB] = E;
}

// bin edges by bucket into ebuf (bucket-grouped, pairs kept in registers)
__global__ __launch_bounds__(256) void k_bin(const int* __restrict__ src,
                                             const int* __restrict__ dst,
                                             int2* __restrict__ ebuf,
                                             int* __restrict__ bcur, int E, int NB) {
    __shared__ int h[256];
    __shared__ int basep[256];
    const int t = threadIdx.x;
    h[t] = 0;
    __syncthreads();
    const int base = blockIdx.x * 4096;
    int s[16], d[16];
#pragma unroll
    for (int k = 0; k < 16; ++k) {
        int e = base + k * 256 + t;
        bool v = e < E;
        s[k] = v ? src[e] : 0;
        d[k] = v ? dst[e] : -1;
        if (v) atomicAdd(&h[d[k] >> NBSHIFT], 1);
    }
    __syncthreads();
    if (t < NB && h[t]) basep[t] = atomicAdd(&bcur[t], h[t]);
    __syncthreads();
    h[t] = 0;
    __syncthreads();
#pragma unroll
    for (int k = 0; k < 16; ++k) {
        if (d[k] >= 0) {
            int b = d[k] >> NBSHIFT;
            int r = atomicAdd(&h[b], 1);
            ebuf[basep[b] + r] = make_int2(s[k], d[k]);
        }
    }
}

// per-bucket: degree count + local scan -> rowstart, dinv, then csr fill via
// LDS cursors. All scatter stays inside the bucket's contiguous csr segment.
__global__ __launch_bounds__(256) void k_bfill(const int2* __restrict__ ebuf,
                                               const int* __restrict__ bbase,
                                               int* __restrict__ csr,
                                               int* __restrict__ rowstart,
                                               float* __restrict__ dinv,
                                               int N, int NB, int E) {
    __shared__ int cnt[512];
    __shared__ int pref[512];
    __shared__ int tsum[256];
    const int t = threadIdx.x;
    const int b = blockIdx.x;
    const int nb0 = b << NBSHIFT;
    const int NN = min(512, N - nb0);
    const int e0 = bbase[b], e1 = bbase[b + 1];

    cnt[t] = 0;
    cnt[t + 256] = 0;
    __syncthreads();
    for (int e = e0 + t; e < e1; e += 256)
        atomicAdd(&cnt[ebuf[e].y - nb0], 1);
    __syncthreads();

    int a0 = cnt[2 * t], a1 = cnt[2 * t + 1];
    tsum[t] = a0 + a1;
    __syncthreads();
    for (int off = 1; off < 256; off <<= 1) {
        int y = (t >= off) ? tsum[t - off] : 0;
        __syncthreads();
        tsum[t] += y;
        __syncthreads();
    }
    int excl = tsum[t] - (a0 + a1);
    pref[2 * t] = excl;
    pref[2 * t + 1] = excl + a0;
    __syncthreads();

    for (int nl = t; nl < NN; nl += 256) {
        rowstart[nb0 + nl] = e0 + pref[nl];
        dinv[nb0 + nl] = rsqrtf((float)(cnt[nl] + 1));  // +1 self loop
    }
    if (b == NB - 1 && t == 0) rowstart[N] = E;
    __syncthreads();  // rowstart reads of pref done before cursor mutation

    for (int e = e0 + t; e < e1; e += 256) {
        int2 ed = ebuf[e];
        int r = atomicAdd(&pref[ed.y - nb0], 1);
        csr[e0 + r] = ed.x;
    }
}

// zero pad rows (node index N) of both colblock-major buffers
__global__ void k_zero_pad(unsigned short* __restrict__ h1b,
                           unsigned short* __restrict__ h2b, int N) {
    int t = threadIdx.x;
    if (t < 128) h1b[((size_t)(t >> 4) * (N + 1) + N) * 16 + (t & 15)] = 0;
    if (t < 64)  h2b[((size_t)(t >> 4) * (N + 1) + N) * 16 + (t & 15)] = 0;
}

// ---------------- W hi/lo split into MFMA B-fragment order ----------------
// Layout: Ws[half][kt][ct][lane][i], half0=hi, half1=lo.
// frag element (lane,i) <-> k = kt*32 + (lane>>4)*8 + i, n = ct*16 + (lane&15).

template <int DOUT_>
__global__ __launch_bounds__(256) void k_wsplit(const float* __restrict__ W,
                                                unsigned short* __restrict__ Ws) {
    constexpr int NCT = DOUT_ / 16;
    constexpr int HALF = 4 * NCT * 64 * 8;
    int id = blockIdx.x * 256 + threadIdx.x;
    if (id >= HALF) return;
    int i = id & 7;
    int lane = (id >> 3) & 63;
    int ctkt = id >> 9;                 // kt*NCT + ct
    int ct = ctkt % NCT, kt = ctkt / NCT;
    int k = kt * 32 + ((lane >> 4) << 3) + i;
    int n = ct * 16 + (lane & 15);
    float v = W[(size_t)k * DOUT_ + n];
    unsigned short h = f2bf(v);
    Ws[id] = h;
    Ws[HALF + id] = f2bf(v - bf2f(h));
}

// -------- MFMA GEMM (fp32 input): H = bf16((X@W)*dinv), X:[N,128] fp32 --------
// Output colblock-major: Hb[ct][(N+1)][16].

template <int DOUT_>
__global__ __launch_bounds__(256) void mfma_gemm(const float* __restrict__ X,
                                                 const unsigned short* __restrict__ Wsplit,
                                                 const float* __restrict__ dinv,
                                                 unsigned short* __restrict__ Hb,
                                                 int N) {
    constexpr int NCT = DOUT_ / 16;
    constexpr int HALF = 4 * NCT * 64 * 8;      // shorts per half
    __shared__ unsigned short lds[2 * HALF];    // 64 KB (D=128)

    const int t = threadIdx.x;
    {
        const int4* s4 = (const int4*)Wsplit;
        int4* d4 = (int4*)lds;
        constexpr int NV = 2 * HALF / 8;
        for (int i = t; i < NV; i += 256) d4[i] = s4[i];
    }
    __syncthreads();

    const int wave = t >> 6, lane = t & 63;
    const int grow = blockIdx.x * 64 + wave * 16 + (lane & 15);
    const int rowc = min(grow, N - 1);
    const int kl = (lane >> 4) << 3;

    floatx4 acc[NCT];
#pragma unroll
    for (int c = 0; c < NCT; ++c) acc[c] = (floatx4)0.f;

#pragma unroll
    for (int kt = 0; kt < 4; ++kt) {
        const float* xp = X + (size_t)rowc * 128 + kt * 32 + kl;
        float4 a0 = *(const float4*)xp;
        float4 a1 = *(const float4*)(xp + 4);
        float xs[8] = {a0.x, a0.y, a0.z, a0.w, a1.x, a1.y, a1.z, a1.w};
        short8 ah, al;
#pragma unroll
        for (int i = 0; i < 8; ++i) {
            unsigned short h = f2bf(xs[i]);
            ah[i] = (short)h;
            al[i] = (short)f2bf(xs[i] - bf2f(h));
        }
#pragma unroll
        for (int c = 0; c < NCT; ++c) {
            const int off = ((kt * NCT + c) * 64 + lane) * 8;
            short8 bh = *(const short8*)&lds[off];
            short8 bl = *(const short8*)&lds[HALF + off];
            acc[c] = __builtin_amdgcn_mfma_f32_16x16x32_bf16(ah, bh, acc[c], 0, 0, 0);
            acc[c] = __builtin_amdgcn_mfma_f32_16x16x32_bf16(al, bh, acc[c], 0, 0, 0);
            acc[c] = __builtin_amdgcn_mfma_f32_16x16x32_bf16(ah, bl, acc[c], 0, 0, 0);
        }
    }

    // C/D layout (verified): col = lane&15, row = (lane>>4)*4 + reg
    const int orow = blockIdx.x * 64 + wave * 16 + ((lane >> 4) << 2);
#pragma unroll
    for (int r = 0; r < 4; ++r) {
        int gr = orow + r;
        if (gr < N) {
            float dn = dinv[gr];
#pragma unroll
            for (int c = 0; c < NCT; ++c)
                Hb[((size_t)c * (N + 1) + gr) * 16 + (lane & 15)] = f2bf(acc[c][r] * dn);
        }
    }
}

// -------- MFMA GEMM (bf16 input, colblock-major): H2 = bf16((Xb@W)*dinv) --------
// Xb: [8][N][16] bf16 (no pad row); output Hb: [NCT][(N+1)][16].

template <int DOUT_>
__global__ __launch_bounds__(256) void mfma_gemm_b(const unsigned short* __restrict__ Xb,
                                                   const unsigned short* __restrict__ Wsplit,
                                                   const float* __restrict__ dinv,
                                                   unsigned short* __restrict__ Hb,
                                                   int N) {
    constexpr int NCT = DOUT_ / 16;
    constexpr int HALF = 4 * NCT * 64 * 8;
    __shared__ unsigned short lds[2 * HALF];    // 32 KB (D=64)

    const int t = threadIdx.x;
    {
        const int4* s4 = (const int4*)Wsplit;
        int4* d4 = (int4*)lds;
        constexpr int NV = 2 * HALF / 8;
        for (int i = t; i < NV; i += 256) d4[i] = s4[i];
    }
    __syncthreads();

    const int wave = t >> 6, lane = t & 63;
    const int grow = blockIdx.x * 64 + wave * 16 + (lane & 15);
    const int rowc = min(grow, N - 1);
    const int kl = (lane >> 4) << 3;

    floatx4 acc[NCT];
#pragma unroll
    for (int c = 0; c < NCT; ++c) acc[c] = (floatx4)0.f;

#pragma unroll
    for (int kt = 0; kt < 4; ++kt) {
        const int k0 = kt * 32 + kl;
        short8 ah = *(const short8*)&Xb[((size_t)(k0 >> 4) * N + rowc) * 16 + (k0 & 15)];
#pragma unroll
        for (int c = 0; c < NCT; ++c) {
            const int off = ((kt * NCT + c) * 64 + lane) * 8;
            short8 bh = *(const short8*)&lds[off];
            short8 bl = *(const short8*)&lds[HALF + off];
            acc[c] = __builtin_amdgcn_mfma_f32_16x16x32_bf16(ah, bh, acc[c], 0, 0, 0);
            acc[c] = __builtin_amdgcn_mfma_f32_16x16x32_bf16(ah, bl, acc[c], 0, 0, 0);
        }
    }

    const int orow = blockIdx.x * 64 + wave * 16 + ((lane >> 4) << 2);
#pragma unroll
    for (int r = 0; r < 4; ++r) {
        int gr = orow + r;
        if (gr < N) {
            float dn = dinv[gr];
#pragma unroll
            for (int c = 0; c < NCT; ++c)
                Hb[((size_t)c * (N + 1) + gr) * 16 + (lane & 15)] = f2bf(acc[c][r] * dn);
        }
    }
}

// ---------------- static XCD-partitioned column-blocked aggregation ----------------
// colblock p = blockIdx&7 (round-robin dispatch -> same-p blocks on one XCD,
// 3.2MB colblock L2-resident). 8-lane group per node: 4B/lane (2 bf16 cols),
// one 32B row per group, 8 rows (=8 lines) per gather instruction. 8 nodes
// per wave, 32 per block. Wave-max degree loop; exhausted slots gather the
// zero pad row (index N, cache-hot) -> branch-free. csr reads are 8x32B
// contiguous runs per instruction, nontemporal (streamed 8x across XCDs).

__global__ __launch_bounds__(256) void agg1_kernel(const unsigned* __restrict__ Hc,  // [8][(N+1)][8] uints
                                                   const int* __restrict__ rowstart,
                                                   const int* __restrict__ csr_src,
                                                   const float* __restrict__ dinv,
                                                   const float* __restrict__ bias,
                                                   unsigned short* __restrict__ outc,  // [8][N][16]
                                                   int N) {
    const int p = blockIdx.x & 7;
    const int chunk = blockIdx.x >> 3;
    const int t = threadIdx.x;
    const int wave = t >> 6, lane = t & 63;
    const int g = lane >> 3, gl = lane & 7;
    const int n = chunk * 32 + wave * 8 + g;
    const bool live = n < N;
    const unsigned* __restrict__ Hp = Hc + (size_t)p * (N + 1) * 8;
    const int e0 = live ? rowstart[n] : 0;
    const int deg = live ? rowstart[n + 1] - e0 : 0;
    int m = deg;
    m = max(m, __shfl_xor(m, 8));
    m = max(m, __shfl_xor(m, 16));
    m = max(m, __shfl_xor(m, 32));

    float a0 = 0.f, a1 = 0.f;
    for (int eb = 0; eb < m; eb += 8) {
        int idx = eb + gl;
        int s_l = (idx < deg) ? __builtin_nontemporal_load(csr_src + e0 + idx) : N;
        int sj[8]; unsigned u[8];
#pragma unroll
        for (int j = 0; j < 8; ++j) sj[j] = __shfl(s_l, (g << 3) | j);
#pragma unroll
        for (int j = 0; j < 8; ++j) u[j] = Hp[(size_t)sj[j] * 8 + gl];
#pragma unroll
        for (int j = 0; j < 8; ++j) { a0 += bf_lo(u[j]); a1 += bf_hi(u[j]); }
    }
    unsigned us = Hp[(size_t)(live ? n : N) * 8 + gl];   // self loop
    a0 += bf_lo(us);
    a1 += bf_hi(us);

    if (live) {
        const float dn = dinv[n];
        const int c0 = p * 16 + gl * 2;
        float o0 = fmaxf(fmaf(a0, dn, bias[c0]), 0.f);      // relu
        float o1 = fmaxf(fmaf(a1, dn, bias[c0 + 1]), 0.f);
        unsigned wv = (unsigned)f2bf(o0) | ((unsigned)f2bf(o1) << 16);
        *reinterpret_cast<unsigned*>(&outc[((size_t)p * N + n) * 16 + gl * 2]) = wv;
    }
}

__global__ __launch_bounds__(256) void agg2_kernel(const unsigned* __restrict__ Hc,  // [4][(N+1)][8] uints
                                                   const int* __restrict__ rowstart,
                                                   const int* __restrict__ csr_src,
                                                   const float* __restrict__ dinv,
                                                   const float* __restrict__ bias,
                                                   float* __restrict__ out,
                                                   int N, int NCH) {
    const int slot = blockIdx.x & 7;
    const int p = slot & 3;
    const int chunk = (blockIdx.x >> 3) * 2 + (slot >> 2);
    if (chunk >= NCH) return;
    const int t = threadIdx.x;
    const int wave = t >> 6, lane = t & 63;
    const int g = lane >> 3, gl = lane & 7;
    const int n = chunk * 32 + wave * 8 + g;
    const bool live = n < N;
    const unsigned* __restrict__ Hp = Hc + (size_t)p * (N + 1) * 8;
    const int e0 = live ? rowstart[n] : 0;
    const int deg = live ? rowstart[n + 1] - e0 : 0;
    int m = deg;
    m = max(m, __shfl_xor(m, 8));
    m = max(m, __shfl_xor(m, 16));
    m = max(m, __shfl_xor(m, 32));

    float a0 = 0.f, a1 = 0.f;
    for (int eb = 0; eb < m; eb += 8) {
        int idx = eb + gl;
        int s_l = (idx < deg) ? __builtin_nontemporal_load(csr_src + e0 + idx) : N;
        int sj[8]; unsigned u[8];
#pragma unroll
        for (int j = 0; j < 8; ++j) sj[j] = __shfl(s_l, (g << 3) | j);
#pragma unroll
        for (int j = 0; j < 8; ++j) u[j] = Hp[(size_t)sj[j] * 8 + gl];
#pragma unroll
        for (int j = 0; j < 8; ++j) { a0 += bf_lo(u[j]); a1 += bf_hi(u[j]); }
    }
    unsigned us = Hp[(size_t)(live ? n : N) * 8 + gl];   // self loop
    a0 += bf_lo(us);
    a1 += bf_hi(us);

    if (live) {
        const float dn = dinv[n];
        const int c0 = p * 16 + gl * 2;
        floatx2 o;
        o.x = fmaf(a0, dn, bias[c0]);
        o.y = fmaf(a1, dn, bias[c0 + 1]);
        *reinterpret_cast<floatx2*>(&out[(size_t)n * 64 + p * 16 + gl * 2]) = o;
    }
}

// ---------------- launch ----------------

extern "C" void kernel_launch(void* const* d_in, const int* in_sizes, int n_in,
                              void* d_out, int out_size, void* d_ws, size_t ws_size,
                              hipStream_t stream) {
    const float* x  = (const float*)d_in[0];
    const int*   ei = (const int*)d_in[1];
    const float* W1 = (const float*)d_in[2];
    const float* b1 = (const float*)d_in[3];
    const float* W2 = (const float*)d_in[4];
    const float* b2 = (const float*)d_in[5];
    float* out = (float*)d_out;

    const int N = in_sizes[0] / D_IN;
    const int E = in_sizes[1] / 2;
    const int* src = ei;
    const int* dst = ei + E;
    const int NB = (N + 511) >> NBSHIFT;   // <= 256

    char* w = (char*)d_ws;
    auto alloc = [&](size_t bytes) {
        char* p = w;
        w += (bytes + 255) & ~(size_t)255;
        return p;
    };
    int*   rowstart  = (int*)alloc((size_t)(N + 1) * 4);
    float* dinv      = (float*)alloc((size_t)N * 4);
    int*   csr       = (int*)alloc((size_t)E * 4);
    unsigned short* h1b = (unsigned short*)alloc((size_t)(N + 1) * D_HID * 2);  // [8][(N+1)][16]
    unsigned short* h2b = (unsigned short*)alloc((size_t)(N + 1) * D_OUT * 2);  // [4][(N+1)][16]
    unsigned short* hgb = (unsigned short*)alloc((size_t)N * D_HID * 2);        // [8][N][16]; also ebuf
    int*   bcnt      = (int*)alloc((size_t)NB * 4);
    int*   bbase     = (int*)alloc((size_t)(NB + 1) * 4);
    int*   bcur      = (int*)alloc((size_t)NB * 4);
    unsigned short* w1s = (unsigned short*)alloc(2 * 4 * (D_HID / 16) * 64 * 8 * 2);
    unsigned short* w2s = (unsigned short*)alloc(2 * 4 * (D_OUT / 16) * 64 * 8 * 2);
    int2*  ebuf      = (int2*)hgb;   // E*8 = 12.8MB <= N*128*2 = 25.6MB; dead before agg1

    k_zero_int<<<1, 256, 0, stream>>>(bcnt, NB);
    k_bhist<<<(E + 8191) / 8192, 256, 0, stream>>>(dst, bcnt, E, NB);
    k_bscan<<<1, 256, 0, stream>>>(bcnt, bbase, bcur, NB, E);
    k_bin<<<(E + 4095) / 4096, 256, 0, stream>>>(src, dst, ebuf, bcur, E, NB);
    k_bfill<<<NB, 256, 0, stream>>>(ebuf, bbase, csr, rowstart, dinv, N, NB, E);
    k_zero_pad<<<1, 128, 0, stream>>>(h1b, h2b, N);
    k_wsplit<D_HID><<<(4 * (D_HID / 16) * 64 * 8 + 255) / 256, 256, 0, stream>>>(W1, w1s);
    k_wsplit<D_OUT><<<(4 * (D_OUT / 16) * 64 * 8 + 255) / 256, 256, 0, stream>>>(W2, w2s);

    const int NCH = (N + 31) / 32;   // 32-node chunks

    mfma_gemm<D_HID><<<(N + 63) / 64, 256, 0, stream>>>(x, w1s, dinv, h1b, N);
    agg1_kernel<<<NCH * 8, 256, 0, stream>>>((const unsigned*)h1b, rowstart, csr,
                                             dinv, b1, hgb, N);
    mfma_gemm_b<D_OUT><<<(N + 63) / 64, 256, 0, stream>>>(hgb, w2s, dinv, h2b, N);
    agg2_kernel<<<((NCH + 1) / 2) * 8, 256, 0, stream>>>((const unsigned*)h2b, rowstart, csr,
                                                         dinv, b2, out, N, NCH);
}

// Round 12
// 204.545 us; speedup vs baseline: 4.1149x; 1.4049x over previous
//
#include <hip/hip_runtime.h>

// GCN 2-layer: out = S·relu(S·(X·W1)+b1)·W2 + b2, S = sym-norm adj + self loops.
// N=100000 nodes, E=1600000 edges, D: 128 -> 128 -> 64.
// GEMMs: MFMA bf16 hi/lo split (fp32-accurate). Aggregation operand stored
// bf16 pre-scaled by dinv[src]; accumulate fp32. agg1 col-half partitioned
// across XCD halves (round-7 structure, best measured). NEW: each node's
// neighbor list is sorted by src octant (src>>14) during CSR build, so the
// aggregation gathers sweep ~1.6MB src windows in phase -> L2-resident
// without re-visiting edges (round 10/11 showed P=8 colblock revisits cost
// 2x despite perfect residency). ebuf packed to 4B/edge; csr/out nontemporal.

#define D_IN  128
#define D_HID 128
#define D_OUT 64
#define NBSHIFT 9           // 512 nodes per bucket; NB = ceil(N/512) <= 256

typedef short short8 __attribute__((ext_vector_type(8)));
typedef float floatx4 __attribute__((ext_vector_type(4)));
typedef float floatx2 __attribute__((ext_vector_type(2)));

__device__ __forceinline__ unsigned short f2bf(float f) {
    unsigned int u = __float_as_uint(f);
    u += 0x7fffu + ((u >> 16) & 1u);   // RNE
    return (unsigned short)(u >> 16);
}
__device__ __forceinline__ float bf2f(unsigned short h) {
    return __uint_as_float((unsigned int)h << 16);
}
__device__ __forceinline__ float bf_lo(unsigned int u) { return __uint_as_float(u << 16); }
__device__ __forceinline__ float bf_hi(unsigned int u) { return __uint_as_float(u & 0xffff0000u); }

// ---------------- graph prep ----------------

__global__ __launch_bounds__(256) void k_zero_int(int* __restrict__ p, int n) {
    int i = blockIdx.x * 256 + threadIdx.x;
    if (i < n) p[i] = 0;
}

// bucket histogram: 8192 edges/block, LDS-reduced, one global add per (block,bucket)
__global__ __launch_bounds__(256) void k_bhist(const int* __restrict__ dst,
                                               int* __restrict__ bcnt, int E, int NB) {
    __shared__ int h[256];
    const int t = threadIdx.x;
    h[t] = 0;
    __syncthreads();
    const int base = blockIdx.x * 8192;
#pragma unroll
    for (int k = 0; k < 32; ++k) {
        int e = base + k * 256 + t;
        if (e < E) atomicAdd(&h[dst[e] >> NBSHIFT], 1);
    }
    __syncthreads();
    if (t < NB && h[t]) atomicAdd(&bcnt[t], h[t]);
}

// exclusive scan of bucket counts (NB <= 256), bases + cursors
__global__ __launch_bounds__(256) void k_bscan(const int* __restrict__ bcnt,
                                               int* __restrict__ bbase,
                                               int* __restrict__ bcur, int NB, int E) {
    __shared__ int ls[256];
    const int t = threadIdx.x;
    int v = (t < NB) ? bcnt[t] : 0;
    ls[t] = v;
    __syncthreads();
    for (int off = 1; off < 256; off <<= 1) {
        int y = (t >= off) ? ls[t - off] : 0;
        __syncthreads();
        ls[t] += y;
        __syncthreads();
    }
    if (t < NB) {
        bbase[t] = ls[t] - v;
        bcur[t]  = ls[t] - v;
    }
    if (t == 0) bbase[NB] = E;
}

// bin edges by bucket into ebuf (bucket-grouped). Packed 4B: (src<<9)|(dst&511).
__global__ __launch_bounds__(256) void k_bin(const int* __restrict__ src,
                                             const int* __restrict__ dst,
                                             int* __restrict__ ebuf,
                                             int* __restrict__ bcur, int E, int NB) {
    __shared__ int h[256];
    __shared__ int basep[256];
    const int t = threadIdx.x;
    h[t] = 0;
    __syncthreads();
    const int base = blockIdx.x * 4096;
    int s[16], d[16];
#pragma unroll
    for (int k = 0; k < 16; ++k) {
        int e = base + k * 256 + t;
        bool v = e < E;
        s[k] = v ? src[e] : 0;
        d[k] = v ? dst[e] : -1;
        if (v) atomicAdd(&h[d[k] >> NBSHIFT], 1);
    }
    __syncthreads();
    if (t < NB && h[t]) basep[t] = atomicAdd(&bcur[t], h[t]);
    __syncthreads();
    h[t] = 0;
    __syncthreads();
#pragma unroll
    for (int k = 0; k < 16; ++k) {
        if (d[k] >= 0) {
            int b = d[k] >> NBSHIFT;
            int r = atomicAdd(&h[b], 1);
            ebuf[basep[b] + r] = (s[k] << 9) | (d[k] & 511);
        }
    }
}

// per-bucket: (dst_local, src_octant) counting sort -> rowstart, dinv, csr.
// Each node's neighbor list comes out sorted by src octant (src>>qshift),
// giving the aggregation kernels a sweeping, L2-resident gather window.
__global__ __launch_bounds__(256) void k_bfill(const int* __restrict__ ebuf,
                                               const int* __restrict__ bbase,
                                               int* __restrict__ csr,
                                               int* __restrict__ rowstart,
                                               float* __restrict__ dinv,
                                               int N, int NB, int E, int qshift) {
    __shared__ int cnt2[512][8];   // counts, then cursors
    __shared__ int nbase[512];
    __shared__ int tsum[256];
    const int t = threadIdx.x;
    const int b = blockIdx.x;
    const int nb0 = b << NBSHIFT;
    const int NN = min(512, N - nb0);
    const int e0 = bbase[b], e1 = bbase[b + 1];

    for (int i = t; i < 512 * 8; i += 256) ((int*)cnt2)[i] = 0;
    __syncthreads();
    for (int e = e0 + t; e < e1; e += 256) {
        int v = ebuf[e];
        int nl = v & 511;
        int o = ((unsigned)v >> 9) >> qshift;
        atomicAdd(&cnt2[nl][o], 1);
    }
    __syncthreads();

    int deg0 = 0, deg1 = 0;
#pragma unroll
    for (int o = 0; o < 8; ++o) {
        deg0 += cnt2[2 * t][o];
        deg1 += cnt2[2 * t + 1][o];
    }
    tsum[t] = deg0 + deg1;
    __syncthreads();
    for (int off = 1; off < 256; off <<= 1) {
        int y = (t >= off) ? tsum[t - off] : 0;
        __syncthreads();
        tsum[t] += y;
        __syncthreads();
    }
    int excl = tsum[t] - (deg0 + deg1);
    nbase[2 * t] = excl;
    nbase[2 * t + 1] = excl + deg0;
    __syncthreads();

    // per-node octant cursors (each thread owns nodes 2t, 2t+1)
#pragma unroll
    for (int k = 0; k < 2; ++k) {
        int nl = 2 * t + k;
        int run = nbase[nl];
#pragma unroll
        for (int o = 0; o < 8; ++o) {
            int c = cnt2[nl][o];
            cnt2[nl][o] = run;
            run += c;
        }
    }
    for (int nl = t; nl < NN; nl += 256) {
        int deg = ((nl < 511 ? nbase[nl + 1] : e1 - e0)) - nbase[nl];
        rowstart[nb0 + nl] = e0 + nbase[nl];
        dinv[nb0 + nl] = rsqrtf((float)(deg + 1));  // +1 self loop
    }
    if (b == NB - 1 && t == 0) rowstart[N] = E;
    __syncthreads();

    for (int e = e0 + t; e < e1; e += 256) {
        int v = ebuf[e];
        int nl = v & 511;
        int srcv = (unsigned)v >> 9;
        int o = srcv >> qshift;
        int r = atomicAdd(&cnt2[nl][o], 1);
        csr[e0 + r] = srcv;
    }
}

// zero the pad row (index N) of both bf16 feature buffers
__global__ void k_zero_pad(unsigned short* __restrict__ h1b,
                           unsigned short* __restrict__ h2b, int N) {
    int t = threadIdx.x;
    if (t < 128) h1b[(size_t)N * 128 + t] = 0;
    if (t < 64)  h2b[(size_t)N * 64 + t] = 0;
}

// ---------------- W hi/lo split into MFMA B-fragment order ----------------
// Layout: Ws[half][kt][ct][lane][i], half0=hi, half1=lo.
// frag element (lane,i) <-> k = kt*32 + (lane>>4)*8 + i, n = ct*16 + (lane&15).

template <int DOUT_>
__global__ __launch_bounds__(256) void k_wsplit(const float* __restrict__ W,
                                                unsigned short* __restrict__ Ws) {
    constexpr int NCT = DOUT_ / 16;
    constexpr int HALF = 4 * NCT * 64 * 8;
    int id = blockIdx.x * 256 + threadIdx.x;
    if (id >= HALF) return;
    int i = id & 7;
    int lane = (id >> 3) & 63;
    int ctkt = id >> 9;                 // kt*NCT + ct
    int ct = ctkt % NCT, kt = ctkt / NCT;
    int k = kt * 32 + ((lane >> 4) << 3) + i;
    int n = ct * 16 + (lane & 15);
    float v = W[(size_t)k * DOUT_ + n];
    unsigned short h = f2bf(v);
    Ws[id] = h;
    Ws[HALF + id] = f2bf(v - bf2f(h));
}

// -------- MFMA GEMM (fp32 input): Hb = bf16((X@W)*dinv), X:[N,128] fp32 --------

template <int DOUT_>
__global__ __launch_bounds__(256) void mfma_gemm(const float* __restrict__ X,
                                                 const unsigned short* __restrict__ Wsplit,
                                                 const float* __restrict__ dinv,
                                                 unsigned short* __restrict__ Hb,
                                                 int N) {
    constexpr int NCT = DOUT_ / 16;
    constexpr int HALF = 4 * NCT * 64 * 8;      // shorts per half
    __shared__ unsigned short lds[2 * HALF];    // 64 KB (D=128)

    const int t = threadIdx.x;
    {
        const int4* s4 = (const int4*)Wsplit;
        int4* d4 = (int4*)lds;
        constexpr int NV = 2 * HALF / 8;
        for (int i = t; i < NV; i += 256) d4[i] = s4[i];
    }
    __syncthreads();

    const int wave = t >> 6, lane = t & 63;
    const int grow = blockIdx.x * 64 + wave * 16 + (lane & 15);
    const int rowc = min(grow, N - 1);
    const int kl = (lane >> 4) << 3;

    floatx4 acc[NCT];
#pragma unroll
    for (int c = 0; c < NCT; ++c) acc[c] = (floatx4)0.f;

#pragma unroll
    for (int kt = 0; kt < 4; ++kt) {
        const float* xp = X + (size_t)rowc * 128 + kt * 32 + kl;
        float4 a0 = *(const float4*)xp;
        float4 a1 = *(const float4*)(xp + 4);
        float xs[8] = {a0.x, a0.y, a0.z, a0.w, a1.x, a1.y, a1.z, a1.w};
        short8 ah, al;
#pragma unroll
        for (int i = 0; i < 8; ++i) {
            unsigned short h = f2bf(xs[i]);
            ah[i] = (short)h;
            al[i] = (short)f2bf(xs[i] - bf2f(h));
        }
#pragma unroll
        for (int c = 0; c < NCT; ++c) {
            const int off = ((kt * NCT + c) * 64 + lane) * 8;
            short8 bh = *(const short8*)&lds[off];
            short8 bl = *(const short8*)&lds[HALF + off];
            acc[c] = __builtin_amdgcn_mfma_f32_16x16x32_bf16(ah, bh, acc[c], 0, 0, 0);
            acc[c] = __builtin_amdgcn_mfma_f32_16x16x32_bf16(al, bh, acc[c], 0, 0, 0);
            acc[c] = __builtin_amdgcn_mfma_f32_16x16x32_bf16(ah, bl, acc[c], 0, 0, 0);
        }
    }

    // C/D layout (verified): col = lane&15, row = (lane>>4)*4 + reg
    const int orow = blockIdx.x * 64 + wave * 16 + ((lane >> 4) << 2);
#pragma unroll
    for (int r = 0; r < 4; ++r) {
        int gr = orow + r;
        if (gr < N) {
            float dn = dinv[gr];
#pragma unroll
            for (int c = 0; c < NCT; ++c)
                Hb[(size_t)gr * DOUT_ + c * 16 + (lane & 15)] = f2bf(acc[c][r] * dn);
        }
    }
}

// -------- MFMA GEMM (bf16 input): Hb = bf16((Xb@W)*dinv), Xb:[N,128] bf16 --------
// A is already bf16 -> no A-lo pass; keep W hi+lo (2 MFMA per tile).

template <int DOUT_>
__global__ __launch_bounds__(256) void mfma_gemm_b(const unsigned short* __restrict__ Xb,
                                                   const unsigned short* __restrict__ Wsplit,
                                                   const float* __restrict__ dinv,
                                                   unsigned short* __restrict__ Hb,
                                                   int N) {
    constexpr int NCT = DOUT_ / 16;
    constexpr int HALF = 4 * NCT * 64 * 8;
    __shared__ unsigned short lds[2 * HALF];    // 32 KB (D=64)

    const int t = threadIdx.x;
    {
        const int4* s4 = (const int4*)Wsplit;
        int4* d4 = (int4*)lds;
        constexpr int NV = 2 * HALF / 8;
        for (int i = t; i < NV; i += 256) d4[i] = s4[i];
    }
    __syncthreads();

    const int wave = t >> 6, lane = t & 63;
    const int grow = blockIdx.x * 64 + wave * 16 + (lane & 15);
    const int rowc = min(grow, N - 1);
    const int kl = (lane >> 4) << 3;

    floatx4 acc[NCT];
#pragma unroll
    for (int c = 0; c < NCT; ++c) acc[c] = (floatx4)0.f;

#pragma unroll
    for (int kt = 0; kt < 4; ++kt) {
        short8 ah = *(const short8*)(Xb + (size_t)rowc * 128 + kt * 32 + kl);
#pragma unroll
        for (int c = 0; c < NCT; ++c) {
            const int off = ((kt * NCT + c) * 64 + lane) * 8;
            short8 bh = *(const short8*)&lds[off];
            short8 bl = *(const short8*)&lds[HALF + off];
            acc[c] = __builtin_amdgcn_mfma_f32_16x16x32_bf16(ah, bh, acc[c], 0, 0, 0);
            acc[c] = __builtin_amdgcn_mfma_f32_16x16x32_bf16(ah, bl, acc[c], 0, 0, 0);
        }
    }

    const int orow = blockIdx.x * 64 + wave * 16 + ((lane >> 4) << 2);
#pragma unroll
    for (int r = 0; r < 4; ++r) {
        int gr = orow + r;
        if (gr < N) {
            float dn = dinv[gr];
#pragma unroll
            for (int c = 0; c < NCT; ++c)
                Hb[(size_t)gr * DOUT_ + c * 16 + (lane & 15)] = f2bf(acc[c][r] * dn);
        }
    }
}

// ---------------- CSR pull aggregation (round-7 shape + octant-sorted lists) ----------------
// agg1: col-half per XCD-half (colhalf = (blockIdx%8)>>2). 8-lane groups x
// 16B = one 128B half-row per gather; 8 nodes/wave, 32/block. Wave-max degree
// loop; exhausted slots gather the zero pad row (index N). csr nontemporal.

__global__ __launch_bounds__(256) void agg1_kernel(const uint4* __restrict__ H4,  // (N+1) x 16 uint4
                                                   const int* __restrict__ rowstart,
                                                   const int* __restrict__ csr_src,
                                                   const float* __restrict__ dinv,
                                                   const float* __restrict__ bias,
                                                   unsigned short* __restrict__ outb,
                                                   int N, int NBK) {
    const int xcd = blockIdx.x & 7;
    const int ch  = xcd >> 2;                       // column half
    const int nb  = (blockIdx.x >> 3) * 4 + (xcd & 3);
    if (nb >= NBK) return;
    const int t = threadIdx.x;
    const int wave = t >> 6, lane = t & 63;
    const int g = lane >> 3, gl = lane & 7;         // 8 groups x 8 lanes
    const int n = nb * 32 + wave * 8 + g;
    const bool live = n < N;
    const int e0 = live ? rowstart[n] : 0;
    const int deg = live ? rowstart[n + 1] - e0 : 0;
    int m = deg;
    m = max(m, __shfl_xor(m, 8));
    m = max(m, __shfl_xor(m, 16));
    m = max(m, __shfl_xor(m, 32));

    const int cb = ch * 8;                          // uint4 offset of column half
    float acc[8] = {0.f, 0.f, 0.f, 0.f, 0.f, 0.f, 0.f, 0.f};
    for (int eb = 0; eb < m; eb += 8) {
        int s_l = (eb + gl < deg)
                      ? __builtin_nontemporal_load(csr_src + e0 + eb + gl)
                      : N;  // N = zero pad row
        int sj[8]; uint4 u[8];
#pragma unroll
        for (int q = 0; q < 8; ++q) sj[q] = __shfl(s_l, (g << 3) | q);
#pragma unroll
        for (int q = 0; q < 8; ++q) u[q] = H4[(size_t)sj[q] * 16 + cb + gl];
#pragma unroll
        for (int q = 0; q < 8; ++q) {
            acc[0] += bf_lo(u[q].x); acc[1] += bf_hi(u[q].x);
            acc[2] += bf_lo(u[q].y); acc[3] += bf_hi(u[q].y);
            acc[4] += bf_lo(u[q].z); acc[5] += bf_hi(u[q].z);
            acc[6] += bf_lo(u[q].w); acc[7] += bf_hi(u[q].w);
        }
    }
    // self loop
    uint4 us = H4[(size_t)(live ? n : N) * 16 + cb + gl];
    acc[0] += bf_lo(us.x); acc[1] += bf_hi(us.x);
    acc[2] += bf_lo(us.y); acc[3] += bf_hi(us.y);
    acc[4] += bf_lo(us.z); acc[5] += bf_hi(us.z);
    acc[6] += bf_lo(us.w); acc[7] += bf_hi(us.w);

    if (live) {
        const float dn = dinv[n];
        const float* bp = bias + ch * 64 + gl * 8;
        unsigned short o[8];
#pragma unroll
        for (int j = 0; j < 8; ++j)
            o[j] = f2bf(fmaxf(fmaf(acc[j], dn, bp[j]), 0.f));  // relu
        *reinterpret_cast<int4*>(&outb[(size_t)n * 128 + ch * 64 + gl * 8]) =
            *reinterpret_cast<const int4*>(o);
    }
}

__global__ __launch_bounds__(256) void agg2_kernel(const uint4* __restrict__ H4,  // (N+1) x 8 uint4
                                                   const int* __restrict__ rowstart,
                                                   const int* __restrict__ csr_src,
                                                   const float* __restrict__ dinv,
                                                   const float* __restrict__ bias,
                                                   float* __restrict__ out, int N) {
    const int t = threadIdx.x;
    const int wave = t >> 6, lane = t & 63;
    const int g = lane >> 3, gl = lane & 7;           // 8 groups x 8 lanes
    const int n = blockIdx.x * 32 + wave * 8 + g;
    const bool live = n < N;
    const int e0 = live ? rowstart[n] : 0;
    const int deg = live ? rowstart[n + 1] - e0 : 0;
    int m = deg;
    m = max(m, __shfl_xor(m, 8));
    m = max(m, __shfl_xor(m, 16));
    m = max(m, __shfl_xor(m, 32));

    float acc[8] = {0.f, 0.f, 0.f, 0.f, 0.f, 0.f, 0.f, 0.f};
    for (int eb = 0; eb < m; eb += 8) {
        int s_l = (eb + gl < deg)
                      ? __builtin_nontemporal_load(csr_src + e0 + eb + gl)
                      : N;
        int sj[8]; uint4 u[8];
#pragma unroll
        for (int q = 0; q < 8; ++q) sj[q] = __shfl(s_l, (g << 3) | q);
#pragma unroll
        for (int q = 0; q < 8; ++q) u[q] = H4[(size_t)sj[q] * 8 + gl];
#pragma unroll
        for (int q = 0; q < 8; ++q) {
            acc[0] += bf_lo(u[q].x); acc[1] += bf_hi(u[q].x);
            acc[2] += bf_lo(u[q].y); acc[3] += bf_hi(u[q].y);
            acc[4] += bf_lo(u[q].z); acc[5] += bf_hi(u[q].z);
            acc[6] += bf_lo(u[q].w); acc[7] += bf_hi(u[q].w);
        }
    }
    uint4 us = H4[(size_t)(live ? n : N) * 8 + gl];
    acc[0] += bf_lo(us.x); acc[1] += bf_hi(us.x);
    acc[2] += bf_lo(us.y); acc[3] += bf_hi(us.y);
    acc[4] += bf_lo(us.z); acc[5] += bf_hi(us.z);
    acc[6] += bf_lo(us.w); acc[7] += bf_hi(us.w);

    if (live) {
        const float dn = dinv[n];
        const float* bp = bias + gl * 8;
        floatx4 o0, o1;
        o0.x = fmaf(acc[0], dn, bp[0]);
        o0.y = fmaf(acc[1], dn, bp[1]);
        o0.z = fmaf(acc[2], dn, bp[2]);
        o0.w = fmaf(acc[3], dn, bp[3]);
        o1.x = fmaf(acc[4], dn, bp[4]);
        o1.y = fmaf(acc[5], dn, bp[5]);
        o1.z = fmaf(acc[6], dn, bp[6]);
        o1.w = fmaf(acc[7], dn, bp[7]);
        float* op = out + (size_t)n * 64 + gl * 8;
        __builtin_nontemporal_store(o0, reinterpret_cast<floatx4*>(op));
        __builtin_nontemporal_store(o1, reinterpret_cast<floatx4*>(op + 4));
    }
}

// ---------------- launch ----------------

extern "C" void kernel_launch(void* const* d_in, const int* in_sizes, int n_in,
                              void* d_out, int out_size, void* d_ws, size_t ws_size,
                              hipStream_t stream) {
    const float* x  = (const float*)d_in[0];
    const int*   ei = (const int*)d_in[1];
    const float* W1 = (const float*)d_in[2];
    const float* b1 = (const float*)d_in[3];
    const float* W2 = (const float*)d_in[4];
    const float* b2 = (const float*)d_in[5];
    float* out = (float*)d_out;

    const int N = in_sizes[0] / D_IN;
    const int E = in_sizes[1] / 2;
    const int* src = ei;
    const int* dst = ei + E;
    const int NB = (N + 511) >> NBSHIFT;   // <= 256
    int qshift = 0;
    while (((N - 1) >> qshift) >= 8) ++qshift;   // 8 src octants

    char* w = (char*)d_ws;
    auto alloc = [&](size_t bytes) {
        char* p = w;
        w += (bytes + 255) & ~(size_t)255;
        return p;
    };
    int*   rowstart  = (int*)alloc((size_t)(N + 1) * 4);
    float* dinv      = (float*)alloc((size_t)N * 4);
    int*   csr       = (int*)alloc((size_t)E * 4);
    unsigned short* h1b = (unsigned short*)alloc((size_t)(N + 1) * D_HID * 2);
    unsigned short* h2b = (unsigned short*)alloc((size_t)(N + 1) * D_OUT * 2);
    unsigned short* hgb = (unsigned short*)alloc((size_t)N * D_HID * 2);  // also ebuf
    int*   bcnt      = (int*)alloc((size_t)NB * 4);
    int*   bbase     = (int*)alloc((size_t)(NB + 1) * 4);
    int*   bcur      = (int*)alloc((size_t)NB * 4);
    unsigned short* w1s = (unsigned short*)alloc(2 * 4 * (D_HID / 16) * 64 * 8 * 2);
    unsigned short* w2s = (unsigned short*)alloc(2 * 4 * (D_OUT / 16) * 64 * 8 * 2);
    int*   ebuf      = (int*)hgb;   // E*4 = 6.4MB <= N*128*2 = 25.6MB; dead before agg1

    k_zero_int<<<1, 256, 0, stream>>>(bcnt, NB);
    k_bhist<<<(E + 8191) / 8192, 256, 0, stream>>>(dst, bcnt, E, NB);
    k_bscan<<<1, 256, 0, stream>>>(bcnt, bbase, bcur, NB, E);
    k_bin<<<(E + 4095) / 4096, 256, 0, stream>>>(src, dst, ebuf, bcur, E, NB);
    k_bfill<<<NB, 256, 0, stream>>>(ebuf, bbase, csr, rowstart, dinv, N, NB, E, qshift);
    k_zero_pad<<<1, 128, 0, stream>>>(h1b, h2b, N);
    k_wsplit<D_HID><<<(4 * (D_HID / 16) * 64 * 8 + 255) / 256, 256, 0, stream>>>(W1, w1s);
    k_wsplit<D_OUT><<<(4 * (D_OUT / 16) * 64 * 8 + 255) / 256, 256, 0, stream>>>(W2, w2s);

    mfma_gemm<D_HID><<<(N + 63) / 64, 256, 0, stream>>>(x, w1s, dinv, h1b, N);

    const int NBK = (N + 31) / 32;                 // node blocks per column half
    agg1_kernel<<<((NBK + 3) / 4) * 8, 256, 0, stream>>>((const uint4*)h1b, rowstart, csr,
                                                         dinv, b1, hgb, N, NBK);
    mfma_gemm_b<D_OUT><<<(N + 63) / 64, 256, 0, stream>>>(hgb, w2s, dinv, h2b, N);
    agg2_kernel<<<(N + 31) / 32, 256, 0, stream>>>((const uint4*)h2b, rowstart, csr,
                                                   dinv, b2, out, N);
}